// Round 6
// baseline (306.336 us; speedup 1.0000x reference)
//
#include <hip/hip_runtime.h>

// LengthRegulator: B=32, T_src=1024, H=512 fixed by the problem.
// d_out layout: [expanded (B*max_len*H) f32][mel_masks (B*max_len) f32(0/1)]
// max_len recovered from out_size = B*max_len*(H+1).
//
// R6 == R5 with the nontemporal-store type fixed (native ext_vector_type,
// since __builtin_nontemporal_store rejects HIP_vector_type structs):
//   - each wave owns a CONTIGUOUS chunk of output rows (x lines land in one
//     XCD L2, once; write bursts are 30 KB contiguous per wave)
//   - register-cache the source row across repeated sidx (avg duration 3.5
//     -> ~70% of row loads skipped, wave-uniform branch, no divergence)
//   - nontemporal output stores (248 MB streaming write doesn't evict x)

#define B_SZ   32
#define T_SRC  1024
#define H_DIM  512

typedef float f32x4 __attribute__((ext_vector_type(4)));

__global__ void __launch_bounds__(T_SRC) lr_prep(const int* __restrict__ dur,
                                                 int* __restrict__ idxbuf,
                                                 float* __restrict__ mask,
                                                 int max_len) {
    __shared__ int s[T_SRC];
    const int b   = blockIdx.x;
    const int tid = threadIdx.x;
    s[tid] = dur[b * T_SRC + tid];
    __syncthreads();
#pragma unroll
    for (int off = 1; off < T_SRC; off <<= 1) {
        int v = (tid >= off) ? s[tid - off] : 0;
        __syncthreads();
        s[tid] += v;
        __syncthreads();
    }
    const int end   = s[tid];
    const int start = tid ? s[tid - 1] : 0;
    const int total = s[T_SRC - 1];

    int* ib = idxbuf + (size_t)b * max_len;
    for (int t = start; t < end; ++t) ib[t] = tid;            // searchsorted == tid
    for (int t = total + tid; t < max_len; t += T_SRC) ib[t] = -1;  // pad
    float* mb = mask + (size_t)b * max_len;
    for (int t = tid; t < max_len; t += T_SRC) mb[t] = (t < total) ? 0.0f : 1.0f;
}

// Grid (GX, B): 4 waves/block, wave w owns rows [w*chunk, (w+1)*chunk).
__global__ void __launch_bounds__(256) lr_copy(const float* __restrict__ x,
                                               const int* __restrict__ idxbuf,
                                               float* __restrict__ out,
                                               int max_len, int chunk) {
    const int b    = blockIdx.y;
    const int lane = threadIdx.x & 63;
    const int wv   = (blockIdx.x << 2) | (threadIdx.x >> 6);

    const int t0 = wv * chunk;
    int t1 = t0 + chunk;
    if (t1 > max_len) t1 = max_len;

    const int*   ib = idxbuf + (size_t)b * max_len;
    const float* xb = x      + (size_t)b * T_SRC   * H_DIM;
    float*       ob = out    + (size_t)b * max_len * H_DIM;

    f32x4 v0 = (f32x4)0.f, v1 = (f32x4)0.f;
    int prev = -2;                       // sentinel != any sidx (incl. -1 pad)

    for (int t = t0; t < t1; ++t) {
        const int sidx = ib[t];          // wave-uniform broadcast load
        if (sidx != prev) {              // wave-uniform branch
            if (sidx >= 0) {
                const f32x4* src = (const f32x4*)(xb + (size_t)sidx * H_DIM);
                v0 = src[lane];
                v1 = src[lane + 64];
            } else {
                v0 = (f32x4)0.f;
                v1 = (f32x4)0.f;
            }
            prev = sidx;
        }
        f32x4* dst = (f32x4*)(ob + (size_t)t * H_DIM);
        __builtin_nontemporal_store(v0, &dst[lane]);
        __builtin_nontemporal_store(v1, &dst[lane + 64]);
    }
}

extern "C" void kernel_launch(void* const* d_in, const int* in_sizes, int n_in,
                              void* d_out, int out_size, void* d_ws, size_t ws_size,
                              hipStream_t stream) {
    const float* x   = (const float*)d_in[0];
    const int*   dur = (const int*)d_in[1];
    float*       out = (float*)d_out;
    int*         idxbuf = (int*)d_ws;   // B_SZ * max_len ints (~480 KB)

    const int max_len = out_size / (B_SZ * (H_DIM + 1));
    float* mask = out + (size_t)B_SZ * max_len * H_DIM;

    lr_prep<<<B_SZ, T_SRC, 0, stream>>>(dur, idxbuf, mask, max_len);

    const int GX     = 64;                       // 64 blocks x 4 waves = 256 waves/batch
    const int nwaves = GX * 4;
    const int chunk  = (max_len + nwaves - 1) / nwaves;
    dim3 grid(GX, B_SZ);
    lr_copy<<<grid, 256, 0, stream>>>(x, idxbuf, out, max_len, chunk);
}